// Round 4
// baseline (1148.855 us; speedup 1.0000x reference)
//
#include <hip/hip_runtime.h>
#include <hip/hip_bf16.h>

typedef _Float16 f16;
typedef _Float16 half8 __attribute__((ext_vector_type(8)));
typedef float f32x4 __attribute__((ext_vector_type(4)));

// Problem constants: B=32, S=1024, D=256, H=256, 4H=1024, M=B*S=32768, Ncat=2048

// ---------------- prep: per-column int8 quantization of U (both dirs) -------
// UQ layout (column-contiguous so the scan can load one column with 16
// global_load_dwordx4 off one base + offset:0..240):
//   dword index ((dir*1024 + j)*16 + kkk)*4 + e,  kkk=0..15, e=0..3
//   element e of uint4 kkk packs U rows k = 16*kkk + 4*e + byte, column j.
__global__ void prep_uq_kernel(const float* __restrict__ Uf, const float* __restrict__ Ur,
                               unsigned int* __restrict__ UQ, float* __restrict__ Uscale)
{
    int idx = blockIdx.x * 256 + threadIdx.x;   // 0..2047 = (dir, j)
    if (idx >= 2048) return;
    int dir = idx >> 10, j = idx & 1023;
    const float* U = dir ? Ur : Uf;
    float m = 0.f;
    for (int k = 0; k < 256; ++k) m = fmaxf(m, fabsf(U[k * 1024 + j]));
    float sinv = (m > 0.f) ? 127.f / m : 0.f;
    for (int kk = 0; kk < 64; ++kk) {
        unsigned int w = 0;
        #pragma unroll
        for (int e = 0; e < 4; ++e) {
            float v = U[(kk * 4 + e) * 1024 + j];
            int q = __float2int_rn(v * sinv);
            w |= ((unsigned int)(q & 0xff)) << (8 * e);
        }
        UQ[(((size_t)dir * 1024 + j) * 16 + (kk >> 2)) * 4 + (kk & 3)] = w;
    }
    Uscale[idx] = m / (127.f * 127.f);  // combined U-scale * h-dequant(1/127)
}

// ---------------- projection GEMM: G[m][n'] = x[m]@W_dir + b_dir (f16) ------
// m = b*1024+s (NOT reversed; reverse handled by scan indexing), n' = dir*1024+g
__global__ __launch_bounds__(256) void proj_gemm_kernel(
    const float* __restrict__ x, const float* __restrict__ Wf, const float* __restrict__ Wr,
    const float* __restrict__ bfw, const float* __restrict__ brw, f16* __restrict__ G)
{
    const int nt = blockIdx.x;           // 0..15  (128-wide n tiles over 2048)
    const int mt = blockIdx.y;           // 0..255 (128-wide m tiles over 32768)
    const int m0 = mt * 128, n0 = nt * 128;
    const int dir = n0 >> 10, nin0 = n0 & 1023;
    const float* W   = dir ? Wr : Wf;
    const float* bia = dir ? brw : bfw;
    __shared__ f16 Asm[128][40];   // [row][k], pad 40 for bank spread
    __shared__ f16 Bsm[128][40];   // [col][k]
    const int t = threadIdx.x;
    const int lane = t & 63, wave = t >> 6;
    const int wr = wave >> 1, wc = wave & 1;      // 2x2 waves, 64x64 each
    f32x4 acc[4][4] = {};
    for (int k0 = 0; k0 < 256; k0 += 32) {
        #pragma unroll
        for (int e = 0; e < 16; ++e) {            // A: 128x32
            int idx = e * 256 + t;
            int r = idx >> 5, kk = idx & 31;
            Asm[r][kk] = (f16)x[(size_t)(m0 + r) * 256 + (k0 + kk)];
        }
        #pragma unroll
        for (int e = 0; e < 16; ++e) {            // B: 32x128 -> [col][k]
            int idx = e * 256 + t;
            int col = idx & 127, kr = idx >> 7;
            Bsm[col][kr] = (f16)W[(size_t)(k0 + kr) * 1024 + (nin0 + col)];
        }
        __syncthreads();
        const int l15 = lane & 15, kb = (lane >> 4) * 8;
        half8 af[4], bfr[4];
        #pragma unroll
        for (int fr = 0; fr < 4; ++fr) af[fr]  = *(const half8*)&Asm[wr * 64 + fr * 16 + l15][kb];
        #pragma unroll
        for (int fc = 0; fc < 4; ++fc) bfr[fc] = *(const half8*)&Bsm[wc * 64 + fc * 16 + l15][kb];
        #pragma unroll
        for (int fr = 0; fr < 4; ++fr)
            #pragma unroll
            for (int fc = 0; fc < 4; ++fc)
                acc[fr][fc] = __builtin_amdgcn_mfma_f32_16x16x32_f16(af[fr], bfr[fc], acc[fr][fc], 0, 0, 0);
        __syncthreads();
    }
    // epilogue: C/D map col=lane&15, row=(lane>>4)*4+i (m89-verified)
    const int row4 = (lane >> 4) * 4, c15 = lane & 15;
    #pragma unroll
    for (int fr = 0; fr < 4; ++fr)
        #pragma unroll
        for (int fc = 0; fc < 4; ++fc) {
            int rbase = m0 + wr * 64 + fr * 16 + row4;
            int cidx  = n0 + wc * 64 + fc * 16 + c15;
            float bv = bia[cidx & 1023];
            #pragma unroll
            for (int i = 0; i < 4; ++i)
                G[(size_t)(rbase + i) * 2048 + cidx] = (f16)(acc[fr][fc][i] + bv);
        }
}

// ---------------- persistent scan: 64 WGs = (dir, batch), 1024 thr ----------
__device__ __forceinline__ int dot4i8(unsigned int a, unsigned int b, int c) {
#if __has_builtin(__builtin_amdgcn_sdot4)
    return __builtin_amdgcn_sdot4(a, b, c, false);
#else
    c += (int)(signed char)(a)       * (int)(signed char)(b);
    c += (int)(signed char)(a >> 8)  * (int)(signed char)(b >> 8);
    c += (int)(signed char)(a >> 16) * (int)(signed char)(b >> 16);
    c += (int)(signed char)(a >> 24) * (int)(signed char)(b >> 24);
    return c;
#endif
}

__device__ __forceinline__ float tanh_fast(float x) {
    float e = __expf(2.f * x);
    return 1.f - 2.f / (e + 1.f);   // exact limits at +-inf, NaN-free
}

// 1024 threads = 16 waves/CU = exactly 4 waves/EU; waves_per_eu(4,4) gives the
// allocator a hard 128-VGPR budget. U loads are issued via asm volatile
// global_load_dwordx4: r1-r3 showed plain loads from a const __restrict__
// pointer are treated as rematerializable and re-streamed from L2 every step
// (~1940 cy/step, the whole bottleneck). asm-volatile defs cannot be remat'd,
// so the 64 VGPRs of U stay live across the loop.
__global__
__attribute__((amdgpu_flat_work_group_size(1024, 1024)))
__attribute__((amdgpu_waves_per_eu(4, 4)))
void scan_kernel(
    const f16* __restrict__ G, const unsigned int* __restrict__ UQ,
    const float* __restrict__ Uscale, float* __restrict__ out)
{
    const int wg = blockIdx.x;
    const int dir = wg >> 5, b = wg & 31;
    const int g = threadIdx.x;                 // gate column 0..1023
    __shared__ __align__(16) unsigned int hq[64];   // h int8[256]
    __shared__ float preact[1024];

    // U column g -> 16 x uint4 (64 VGPRs), forced resident
    const uint4* up = (const uint4*)(UQ + (((size_t)dir * 1024 + g) << 6));
    uint4 ureg[16];
    #pragma unroll
    for (int kkk = 0; kkk < 16; ++kkk)
        asm volatile("global_load_dwordx4 %0, %1, off offset:%2"
                     : "=v"(ureg[kkk]) : "v"(up), "i"(kkk * 16));
    asm volatile("s_waitcnt vmcnt(0)" ::: "memory");
    __builtin_amdgcn_sched_barrier(0);

    const float usc = Uscale[dir * 1024 + g];

    float c_state = 0.f;                       // valid for g < 256
    if (g < 64) hq[g] = 0u;                    // h0 = 0
    const long stride = dir ? -2048 : 2048;
    const f16* gp = G + (size_t)b * 1024 * 2048 + dir * 1024 + g
                      + (dir ? (size_t)1023 * 2048 : 0);
    float* outp = out + (size_t)b * 1024 * 512 + dir * 256 + g;  // used by g<256
    f16 xw_c = *gp;                            // prefetch step 0
    __syncthreads();

    for (int t = 0; t < 1024; ++t) {
        const f16* gn = gp + ((t < 1023) ? stride : 0);
        f16 xw_n = *gn;                        // prefetch next step's xW

        int i0 = 0, i1 = 0, i2 = 0, i3 = 0;    // split chain for ILP
        #pragma unroll
        for (int kkk = 0; kkk < 16; ++kkk) {
            uint4 h4 = *(const uint4*)&hq[kkk * 4];   // wave-uniform b128 broadcast
            i0 = dot4i8(ureg[kkk].x, h4.x, i0);
            i1 = dot4i8(ureg[kkk].y, h4.y, i1);
            i2 = dot4i8(ureg[kkk].z, h4.z, i2);
            i3 = dot4i8(ureg[kkk].w, h4.w, i3);
        }
        int iacc = (i0 + i1) + (i2 + i3);
        preact[g] = (float)xw_c + (float)iacc * usc;
        __syncthreads();

        if (g < 256) {
            float pi = preact[g];
            float pf = preact[256 + g];
            float pg = preact[512 + g];
            float po = preact[768 + g];
            float ig = 1.f / (1.f + __expf(-pi));
            float fg = 1.f / (1.f + __expf(-pf));
            float gg = tanh_fast(pg);
            float og = 1.f / (1.f + __expf(-po));
            c_state = fg * c_state + ig * gg;
            float h = og * tanh_fast(c_state);
            int s = dir ? (1023 - t) : t;
            outp[(size_t)s * 512] = h;
            int iq = __float2int_rn(h * 127.f);
            ((signed char*)hq)[g] = (signed char)iq;
        }
        __syncthreads();
        xw_c = xw_n;
        gp = gn;
    }
}

extern "C" void kernel_launch(void* const* d_in, const int* in_sizes, int n_in,
                              void* d_out, int out_size, void* d_ws, size_t ws_size,
                              hipStream_t stream) {
    const float* x  = (const float*)d_in[0];
    const float* Wf = (const float*)d_in[1];
    const float* Uf = (const float*)d_in[2];
    const float* bf = (const float*)d_in[3];
    const float* Wr = (const float*)d_in[4];
    const float* Ur = (const float*)d_in[5];
    const float* br = (const float*)d_in[6];
    float* out = (float*)d_out;

    char* ws = (char*)d_ws;
    unsigned int* UQ = (unsigned int*)ws;                       // 512 KB
    float* Uscale    = (float*)(ws + (size_t)512 * 1024);       // 8 KB
    f16* G           = (f16*)(ws + (size_t)1024 * 1024);        // 128 MB

    prep_uq_kernel<<<8, 256, 0, stream>>>(Uf, Ur, UQ, Uscale);
    dim3 gg(16, 256);
    proj_gemm_kernel<<<gg, 256, 0, stream>>>(x, Wf, Wr, bf, br, G);
    scan_kernel<<<64, 1024, 0, stream>>>(G, UQ, Uscale, out);
}

// Round 5
// 1131.634 us; speedup vs baseline: 1.0152x; 1.0152x over previous
//
#include <hip/hip_runtime.h>
#include <hip/hip_bf16.h>

typedef _Float16 f16;
typedef _Float16 half8 __attribute__((ext_vector_type(8)));
typedef float f32x4 __attribute__((ext_vector_type(4)));

// Problem constants: B=32, S=1024, D=256, H=256, 4H=1024, M=B*S=32768, Ncat=2048

// ---------------- prep: per-column int8 quantization of U (both dirs) -------
// UQ layout (column-contiguous so the scan can load one column with 16
// global_load_dwordx4 off one base + offset:0..240):
//   dword index ((dir*1024 + j)*16 + kkk)*4 + e,  kkk=0..15, e=0..3
//   element e of uint4 kkk packs U rows k = 16*kkk + 4*e + byte, column j.
__global__ void prep_uq_kernel(const float* __restrict__ Uf, const float* __restrict__ Ur,
                               unsigned int* __restrict__ UQ, float* __restrict__ Uscale)
{
    int idx = blockIdx.x * 256 + threadIdx.x;   // 0..2047 = (dir, j)
    if (idx >= 2048) return;
    int dir = idx >> 10, j = idx & 1023;
    const float* U = dir ? Ur : Uf;
    float m = 0.f;
    for (int k = 0; k < 256; ++k) m = fmaxf(m, fabsf(U[k * 1024 + j]));
    float sinv = (m > 0.f) ? 127.f / m : 0.f;
    for (int kk = 0; kk < 64; ++kk) {
        unsigned int w = 0;
        #pragma unroll
        for (int e = 0; e < 4; ++e) {
            float v = U[(kk * 4 + e) * 1024 + j];
            int q = __float2int_rn(v * sinv);
            w |= ((unsigned int)(q & 0xff)) << (8 * e);
        }
        UQ[(((size_t)dir * 1024 + j) * 16 + (kk >> 2)) * 4 + (kk & 3)] = w;
    }
    Uscale[idx] = m / (127.f * 127.f);  // combined U-scale * h-dequant(1/127)
}

// ---------------- projection GEMM: G[m][n'] = x[m]@W_dir + b_dir (f16) ------
// m = b*1024+s (NOT reversed; reverse handled by scan indexing), n' = dir*1024+g
__global__ __launch_bounds__(256) void proj_gemm_kernel(
    const float* __restrict__ x, const float* __restrict__ Wf, const float* __restrict__ Wr,
    const float* __restrict__ bfw, const float* __restrict__ brw, f16* __restrict__ G)
{
    const int nt = blockIdx.x;           // 0..15  (128-wide n tiles over 2048)
    const int mt = blockIdx.y;           // 0..255 (128-wide m tiles over 32768)
    const int m0 = mt * 128, n0 = nt * 128;
    const int dir = n0 >> 10, nin0 = n0 & 1023;
    const float* W   = dir ? Wr : Wf;
    const float* bia = dir ? brw : bfw;
    __shared__ f16 Asm[128][40];   // [row][k], pad 40 for bank spread
    __shared__ f16 Bsm[128][40];   // [col][k]
    const int t = threadIdx.x;
    const int lane = t & 63, wave = t >> 6;
    const int wr = wave >> 1, wc = wave & 1;      // 2x2 waves, 64x64 each
    f32x4 acc[4][4] = {};
    for (int k0 = 0; k0 < 256; k0 += 32) {
        #pragma unroll
        for (int e = 0; e < 16; ++e) {            // A: 128x32
            int idx = e * 256 + t;
            int r = idx >> 5, kk = idx & 31;
            Asm[r][kk] = (f16)x[(size_t)(m0 + r) * 256 + (k0 + kk)];
        }
        #pragma unroll
        for (int e = 0; e < 16; ++e) {            // B: 32x128 -> [col][k]
            int idx = e * 256 + t;
            int col = idx & 127, kr = idx >> 7;
            Bsm[col][kr] = (f16)W[(size_t)(k0 + kr) * 1024 + (nin0 + col)];
        }
        __syncthreads();
        const int l15 = lane & 15, kb = (lane >> 4) * 8;
        half8 af[4], bfr[4];
        #pragma unroll
        for (int fr = 0; fr < 4; ++fr) af[fr]  = *(const half8*)&Asm[wr * 64 + fr * 16 + l15][kb];
        #pragma unroll
        for (int fc = 0; fc < 4; ++fc) bfr[fc] = *(const half8*)&Bsm[wc * 64 + fc * 16 + l15][kb];
        #pragma unroll
        for (int fr = 0; fr < 4; ++fr)
            #pragma unroll
            for (int fc = 0; fc < 4; ++fc)
                acc[fr][fc] = __builtin_amdgcn_mfma_f32_16x16x32_f16(af[fr], bfr[fc], acc[fr][fc], 0, 0, 0);
        __syncthreads();
    }
    // epilogue: C/D map col=lane&15, row=(lane>>4)*4+i (m89-verified)
    const int row4 = (lane >> 4) * 4, c15 = lane & 15;
    #pragma unroll
    for (int fr = 0; fr < 4; ++fr)
        #pragma unroll
        for (int fc = 0; fc < 4; ++fc) {
            int rbase = m0 + wr * 64 + fr * 16 + row4;
            int cidx  = n0 + wc * 64 + fc * 16 + c15;
            float bv = bia[cidx & 1023];
            #pragma unroll
            for (int i = 0; i < 4; ++i)
                G[(size_t)(rbase + i) * 2048 + cidx] = (f16)(acc[fr][fc][i] + bv);
        }
}

// ---------------- persistent scan: 64 WGs = (dir, batch), 1024 thr ----------
__device__ __forceinline__ int dot4i8(unsigned int a, unsigned int b, int c) {
#if __has_builtin(__builtin_amdgcn_sdot4)
    return __builtin_amdgcn_sdot4(a, b, c, false);
#else
    c += (int)(signed char)(a)       * (int)(signed char)(b);
    c += (int)(signed char)(a >> 8)  * (int)(signed char)(b >> 8);
    c += (int)(signed char)(a >> 16) * (int)(signed char)(b >> 16);
    c += (int)(signed char)(a >> 24) * (int)(signed char)(b >> 24);
    return c;
#endif
}

__device__ __forceinline__ float tanh_fast(float x) {
    float e = __expf(2.f * x);
    return 1.f - 2.f / (e + 1.f);   // exact limits at +-inf, NaN-free
}

// 1024 threads = 16 waves/CU = exactly 4 waves/EU; waves_per_eu(4,4) => hard
// 128-VGPR budget. U loads via asm volatile (cannot be remat'd - r3 showed
// plain invariant loads get re-streamed). r4 showed asm alone still spilled:
// the fully-hoisted 16x ds_read_b128 h-buffers pushed in-loop pressure to
// ~150 > 128, so the allocator spilled the loop-invariant ureg to scratch
// (16 reloads/step = same L2 traffic as streaming). Fix: sched_barrier(0)
// fences every 4 h-reads so only 16 h regs are live at once; max pressure
// ~105 < 128 -> ureg stays in VGPRs. Validation: VGPR_Count must jump ~52->110.
__global__
__attribute__((amdgpu_flat_work_group_size(1024, 1024)))
__attribute__((amdgpu_waves_per_eu(4, 4)))
void scan_kernel(
    const f16* __restrict__ G, const unsigned int* __restrict__ UQ,
    const float* __restrict__ Uscale, float* __restrict__ out)
{
    const int wg = blockIdx.x;
    const int dir = wg >> 5, b = wg & 31;
    const int g = threadIdx.x;                 // gate column 0..1023
    __shared__ __align__(16) unsigned int hq[64];   // h int8[256]
    __shared__ float preact[1024];

    // U column g -> 16 x uint4 (64 VGPRs), forced resident
    const uint4* up = (const uint4*)(UQ + (((size_t)dir * 1024 + g) << 6));
    uint4 ureg[16];
    #pragma unroll
    for (int kkk = 0; kkk < 16; ++kkk)
        asm volatile("global_load_dwordx4 %0, %1, off offset:%2"
                     : "=v"(ureg[kkk]) : "v"(up), "i"(kkk * 16));
    asm volatile("s_waitcnt vmcnt(0)" ::: "memory");
    __builtin_amdgcn_sched_barrier(0);

    const float usc = Uscale[dir * 1024 + g];

    float c_state = 0.f;                       // valid for g < 256
    if (g < 64) hq[g] = 0u;                    // h0 = 0
    const long stride = dir ? -2048 : 2048;
    const f16* gp = G + (size_t)b * 1024 * 2048 + dir * 1024 + g
                      + (dir ? (size_t)1023 * 2048 : 0);
    float* outp = out + (size_t)b * 1024 * 512 + dir * 256 + g;  // used by g<256
    f16 xw_c = *gp;                            // prefetch step 0
    __syncthreads();

    const uint4* hp4 = (const uint4*)hq;

    for (int t = 0; t < 1024; ++t) {
        const f16* gn = gp + ((t < 1023) ? stride : 0);
        f16 xw_n = *gn;                        // prefetch next step's xW

        int i0 = 0, i1 = 0, i2 = 0, i3 = 0;    // split chain for ILP
        #pragma unroll
        for (int ch = 0; ch < 4; ++ch) {
            // region: 4 x ds_read_b128 (wave-uniform broadcast) + 16 dot4.
            // sched_barrier(0) stops the scheduler hoisting the next chunk's
            // h-reads into this one (keeps live h regs at 16, not 64).
            uint4 ha = hp4[ch * 4 + 0];
            uint4 hb = hp4[ch * 4 + 1];
            uint4 hc = hp4[ch * 4 + 2];
            uint4 hd = hp4[ch * 4 + 3];
            i0 = dot4i8(ureg[ch * 4 + 0].x, ha.x, i0);
            i1 = dot4i8(ureg[ch * 4 + 0].y, ha.y, i1);
            i2 = dot4i8(ureg[ch * 4 + 0].z, ha.z, i2);
            i3 = dot4i8(ureg[ch * 4 + 0].w, ha.w, i3);
            i0 = dot4i8(ureg[ch * 4 + 1].x, hb.x, i0);
            i1 = dot4i8(ureg[ch * 4 + 1].y, hb.y, i1);
            i2 = dot4i8(ureg[ch * 4 + 1].z, hb.z, i2);
            i3 = dot4i8(ureg[ch * 4 + 1].w, hb.w, i3);
            i0 = dot4i8(ureg[ch * 4 + 2].x, hc.x, i0);
            i1 = dot4i8(ureg[ch * 4 + 2].y, hc.y, i1);
            i2 = dot4i8(ureg[ch * 4 + 2].z, hc.z, i2);
            i3 = dot4i8(ureg[ch * 4 + 2].w, hc.w, i3);
            i0 = dot4i8(ureg[ch * 4 + 3].x, hd.x, i0);
            i1 = dot4i8(ureg[ch * 4 + 3].y, hd.y, i1);
            i2 = dot4i8(ureg[ch * 4 + 3].z, hd.z, i2);
            i3 = dot4i8(ureg[ch * 4 + 3].w, hd.w, i3);
            __builtin_amdgcn_sched_barrier(0);
        }
        int iacc = (i0 + i1) + (i2 + i3);
        preact[g] = (float)xw_c + (float)iacc * usc;
        __syncthreads();

        if (g < 256) {
            float pi = preact[g];
            float pf = preact[256 + g];
            float pg = preact[512 + g];
            float po = preact[768 + g];
            float ig = 1.f / (1.f + __expf(-pi));
            float fg = 1.f / (1.f + __expf(-pf));
            float gg = tanh_fast(pg);
            float og = 1.f / (1.f + __expf(-po));
            c_state = fg * c_state + ig * gg;
            float h = og * tanh_fast(c_state);
            int s = dir ? (1023 - t) : t;
            outp[(size_t)s * 512] = h;
            int iq = __float2int_rn(h * 127.f);
            ((signed char*)hq)[g] = (signed char)iq;
        }
        __syncthreads();
        xw_c = xw_n;
        gp = gn;
    }
}

extern "C" void kernel_launch(void* const* d_in, const int* in_sizes, int n_in,
                              void* d_out, int out_size, void* d_ws, size_t ws_size,
                              hipStream_t stream) {
    const float* x  = (const float*)d_in[0];
    const float* Wf = (const float*)d_in[1];
    const float* Uf = (const float*)d_in[2];
    const float* bf = (const float*)d_in[3];
    const float* Wr = (const float*)d_in[4];
    const float* Ur = (const float*)d_in[5];
    const float* br = (const float*)d_in[6];
    float* out = (float*)d_out;

    char* ws = (char*)d_ws;
    unsigned int* UQ = (unsigned int*)ws;                       // 512 KB
    float* Uscale    = (float*)(ws + (size_t)512 * 1024);       // 8 KB
    f16* G           = (f16*)(ws + (size_t)1024 * 1024);        // 128 MB

    prep_uq_kernel<<<8, 256, 0, stream>>>(Uf, Ur, UQ, Uscale);
    dim3 gg(16, 256);
    proj_gemm_kernel<<<gg, 256, 0, stream>>>(x, Wf, Wr, bf, br, G);
    scan_kernel<<<64, 1024, 0, stream>>>(G, UQ, Uscale, out);
}